// Round 1
// 436.992 us; speedup vs baseline: 1.0277x; 1.0277x over previous
//
#include <hip/hip_runtime.h>
#include <stdint.h>

#define B_ROWS 8192
#define IN_DIM 4096
#define OUT_DIM 4096
#define BN_EPS 1e-5f

#define BM 256                      // batch rows per block
#define BLKN 256                    // out cols per block
#define BKB 128                     // i8 K-bytes per K-tile
#define NKT (IN_DIM / BKB)          // 32 K-tiles
#define NIT (NKT / 2)               // 16 iterations (2 K-tiles each)

typedef __attribute__((ext_vector_type(4))) int i32x4;

// ---------------------------------------------------------------------------
// fp32 -> int8 sign pack: {-1, 0, +1}. Exact.
// ---------------------------------------------------------------------------
__device__ __forceinline__ int sign_byte(float f) {
    int s = (f > 0.f) ? 1 : ((f < 0.f) ? -1 : 0);
    return s & 0xFF;
}

__global__ void pack_i8(const float* __restrict__ in, int* __restrict__ out) {
    int gid = blockIdx.x * blockDim.x + threadIdx.x;
    float4 v = reinterpret_cast<const float4*>(in)[gid];
    out[gid] = sign_byte(v.x) | (sign_byte(v.y) << 8) |
               (sign_byte(v.z) << 16) | (sign_byte(v.w) << 24);
}

// ---------------------------------------------------------------------------
// 256x256 8-phase i8 MFMA GEMM (m201/m204 template ported to i8 16x16x64).
//
// LDS: 2 K-tile buffers x (A 32KB + B 32KB) = 128 KiB. Rows are 128 B = 8
// 16-B slots; slot is XOR-swizzled with (row&7) -> ds_read_b128 is 2-way
// max (free). global_load_lds dest is linear (base+lane*16); the swizzle is
// applied to the per-lane *global* source address (same involution).
//
// Schedule per iteration (2 K-tiles, buffers b0/b1), quadrants:
//   ph1: rd b0.A(mf0-3)+B(nf0-1) [12]  stage b1.BN1   mfma Q(0-3,0-1)
//   ph2: rd b0.A(mf4-7)          [ 8]  stage b0'.AQ0  mfma Q(4-7,0-1)
//   ph3: rd b0.B(nf2-3)          [ 4]  stage b0'.AQ1  mfma Q(4-7,2-3)
//   ph4:                         [ 0]  stage b0'.BN0  mfma Q(0-3,2-3)  vmcnt(6)
//   ph5-8: same on b1 (stages b0'.BN1, b1'.AQ0, b1'.AQ1, b1'.BN0)      vmcnt(6)
// Each stage lands only in a region whose last ds_read drained >=1 phase
// earlier; vmcnt(6) (= 3 half-tiles in flight) at ph4/ph8 guarantees the
// next buffer is complete. Never vmcnt(0) in the main loop.
// ---------------------------------------------------------------------------
__device__ __forceinline__ void stage_pair(const int8_t* g0, int8_t* l0) {
    __builtin_amdgcn_global_load_lds(
        (const __attribute__((address_space(1))) void*)g0,
        (__attribute__((address_space(3))) void*)l0, 16, 0, 0);
    __builtin_amdgcn_global_load_lds(
        (const __attribute__((address_space(1))) void*)(g0 + (size_t)128 * IN_DIM),
        (__attribute__((address_space(3))) void*)(l0 + 128 * BKB), 16, 0, 0);
}

template <int FB>
__device__ __forceinline__ void load_frag4(i32x4 d[4][2], const int8_t* base,
                                           int off0, int off1) {
#pragma unroll
    for (int f = 0; f < 4; ++f) {
        d[f][0] = *reinterpret_cast<const i32x4*>(base + (FB + f) * (16 * BKB) + off0);
        d[f][1] = *reinterpret_cast<const i32x4*>(base + (FB + f) * (16 * BKB) + off1);
    }
}

template <int FB>
__device__ __forceinline__ void load_frag2(i32x4 d[2][2], const int8_t* base,
                                           int off0, int off1) {
#pragma unroll
    for (int f = 0; f < 2; ++f) {
        d[f][0] = *reinterpret_cast<const i32x4*>(base + (FB + f) * (16 * BKB) + off0);
        d[f][1] = *reinterpret_cast<const i32x4*>(base + (FB + f) * (16 * BKB) + off1);
    }
}

template <int AM, int AN>
__device__ __forceinline__ void mfma_quad(i32x4 acc[8][4], const i32x4 a[4][2],
                                          const i32x4 b[2][2]) {
#pragma unroll
    for (int mf = 0; mf < 4; ++mf)
#pragma unroll
        for (int nf = 0; nf < 2; ++nf) {
            acc[AM + mf][AN + nf] = __builtin_amdgcn_mfma_i32_16x16x64_i8(
                a[mf][0], b[nf][0], acc[AM + mf][AN + nf], 0, 0, 0);
            acc[AM + mf][AN + nf] = __builtin_amdgcn_mfma_i32_16x16x64_i8(
                a[mf][1], b[nf][1], acc[AM + mf][AN + nf], 0, 0, 0);
        }
}

#define PHASE_MID()                                             \
    __builtin_amdgcn_s_barrier();                               \
    asm volatile("s_waitcnt lgkmcnt(0)" ::: "memory");          \
    __builtin_amdgcn_sched_barrier(0);                          \
    __builtin_amdgcn_s_setprio(1)

#define PHASE_END()                                             \
    __builtin_amdgcn_s_setprio(0);                              \
    __builtin_amdgcn_s_barrier()

#define PHASE_END_VM()                                          \
    __builtin_amdgcn_s_setprio(0);                              \
    asm volatile("s_waitcnt vmcnt(6)" ::: "memory");            \
    __builtin_amdgcn_s_barrier()

__global__ __launch_bounds__(512, 2) void bin_gemm_i8(
    const int8_t* __restrict__ A,    // [B_ROWS][IN_DIM] i8
    const int8_t* __restrict__ W,    // [OUT_DIM][IN_DIM] i8
    float* __restrict__ out,         // [B_ROWS][OUT_DIM] f32 (raw dot)
    float* __restrict__ colsum,
    float* __restrict__ colsumsq)
{
    __shared__ __align__(16) int8_t lds[2][2][BM * BKB];   // [buf][A=0/B=1] 128 KiB
    __shared__ float s_sum[BLKN];
    __shared__ float s_sq[BLKN];

    const int t      = threadIdx.x;
    const int lane   = t & 63;
    const int wave   = t >> 6;
    const int wm     = wave >> 2;          // 0..1
    const int wn     = wave & 3;           // 0..3
    const int lane16 = lane & 15;
    const int quad   = lane >> 4;

    // XCD-aware bijective block swizzle (512 workgroups, 512 % 8 == 0)
    const int flat = blockIdx.y * gridDim.x + blockIdx.x;
    const int swz  = (flat & 7) * (512 / 8) + (flat >> 3);
    const int row0 = (swz >> 4) * BM;      // batch-row block
    const int col0 = (swz & 15) * BLKN;    // out-col block

    if (t < BLKN) { s_sum[t] = 0.f; s_sq[t] = 0.f; }

    // ---- staging geometry: thread -> (row, 16B slot), swizzled global src ----
    const int r6 = t >> 3;                       // 0..63
    const int c8 = t & 7;                        // phys slot in 128-B row
    const int gslot = ((c8 ^ (r6 & 7)) << 4);    // swizzled global 16-B group
    const int rA0 = r6;                          // A rows: +{0,64} sel, +128 load1
    const int rB0 = r6 + (r6 & 32);              // B rows: +{0,32} sel, +128 load1

    const int8_t* pA = A + (size_t)(row0 + rA0) * IN_DIM + gslot;
    const int8_t* pW = W + (size_t)(col0 + rB0) * IN_DIM + gslot;
    int8_t* lA0 = &lds[0][0][rA0 * BKB + c8 * 16];
    int8_t* lB0 = &lds[0][1][rB0 * BKB + c8 * 16];

    // ---- read geometry: frag row = base+f*16+lane16; slot=(ks*4+quad)^row&7 ----
    const int sw   = lane & 7;
    const int off0 = ((quad ^ sw) << 4);
    const int off1 = (((4 + quad) ^ sw) << 4);
    const int8_t* rA = &lds[0][0][(wm * 128 + lane16) * BKB];
    const int8_t* rB = &lds[0][1][(wn * 64 + lane16) * BKB];

    i32x4 acc[8][4] = {};
    i32x4 alo[4][2], ahi[4][2], bb[2][2];

    // ---- prologue: tile0 -> buf0 full; tile1 -> buf1 AQ0,AQ1,BN0 (14 loads) ----
    stage_pair(pA,                             lA0);                        // b0.AQ0
    stage_pair(pA + (size_t)64 * IN_DIM,       lA0 + 64 * BKB);             // b0.AQ1
    stage_pair(pW,                             lB0);                        // b0.BN0
    stage_pair(pW + (size_t)32 * IN_DIM,       lB0 + 32 * BKB);             // b0.BN1
    stage_pair(pA + BKB,                       lA0 + 65536);                // b1.AQ0
    stage_pair(pA + (size_t)64 * IN_DIM + BKB, lA0 + 65536 + 64 * BKB);     // b1.AQ1
    stage_pair(pW + BKB,                       lB0 + 65536);                // b1.BN0
    asm volatile("s_waitcnt vmcnt(6)" ::: "memory");                        // b0 done
    __builtin_amdgcn_s_barrier();

#pragma unroll 1
    for (int it = 0; it < NIT; ++it) {
        const int tc1 = (2 * it + 1) & (NKT - 1);
        const int tn0 = (2 * it + 2) & (NKT - 1);   // wraps harmlessly on last iter
        const int tn1 = (2 * it + 3) & (NKT - 1);

        // ================= K-tile in buf0 =================
        // phase 1
        load_frag4<0>(alo, rA, off0, off1);
        load_frag2<0>(bb, rB, off0, off1);
        stage_pair(pW + (size_t)32 * IN_DIM + tc1 * BKB, lB0 + 65536 + 32 * BKB);
        PHASE_MID();
        mfma_quad<0, 0>(acc, alo, bb);
        PHASE_END();

        // phase 2
        load_frag4<4>(ahi, rA, off0, off1);
        stage_pair(pA + tn0 * BKB, lA0);
        PHASE_MID();
        mfma_quad<4, 0>(acc, ahi, bb);
        PHASE_END();

        // phase 3
        load_frag2<2>(bb, rB, off0, off1);
        stage_pair(pA + (size_t)64 * IN_DIM + tn0 * BKB, lA0 + 64 * BKB);
        PHASE_MID();
        mfma_quad<4, 2>(acc, ahi, bb);
        PHASE_END();

        // phase 4
        stage_pair(pW + tn0 * BKB, lB0);
        PHASE_MID();
        mfma_quad<0, 2>(acc, alo, bb);
        PHASE_END_VM();

        // ================= K-tile in buf1 =================
        // phase 5
        load_frag4<0>(alo, rA + 65536, off0, off1);
        load_frag2<0>(bb, rB + 65536, off0, off1);
        stage_pair(pW + (size_t)32 * IN_DIM + tn0 * BKB, lB0 + 32 * BKB);
        PHASE_MID();
        mfma_quad<0, 0>(acc, alo, bb);
        PHASE_END();

        // phase 6
        load_frag4<4>(ahi, rA + 65536, off0, off1);
        stage_pair(pA + tn1 * BKB, lA0 + 65536);
        PHASE_MID();
        mfma_quad<4, 0>(acc, ahi, bb);
        PHASE_END();

        // phase 7
        load_frag2<2>(bb, rB + 65536, off0, off1);
        stage_pair(pA + (size_t)64 * IN_DIM + tn1 * BKB, lA0 + 65536 + 64 * BKB);
        PHASE_MID();
        mfma_quad<4, 2>(acc, ahi, bb);
        PHASE_END();

        // phase 8
        stage_pair(pW + tn1 * BKB, lB0 + 65536);
        PHASE_MID();
        mfma_quad<0, 2>(acc, alo, bb);
        PHASE_END_VM();
    }

    // ---- epilogue: write fp32 C, accumulate per-column BN partials ----
    float csum[4] = {0.f, 0.f, 0.f, 0.f};
    float csq[4]  = {0.f, 0.f, 0.f, 0.f};
#pragma unroll
    for (int mf = 0; mf < 8; ++mf) {
#pragma unroll
        for (int r = 0; r < 4; ++r) {
            int grow = row0 + wm * 128 + mf * 16 + quad * 4 + r;   // C/D row=quad*4+reg
            float* orow = out + (size_t)grow * OUT_DIM + col0 + wn * 64 + lane16;
#pragma unroll
            for (int nf = 0; nf < 4; ++nf) {
                float v = (float)acc[mf][nf][r];
                orow[nf * 16] = v;
                csum[nf] += v;
                csq[nf]  += v * v;
            }
        }
    }
#pragma unroll
    for (int nf = 0; nf < 4; ++nf) {
        csum[nf] += __shfl_xor(csum[nf], 16);
        csum[nf] += __shfl_xor(csum[nf], 32);
        csq[nf]  += __shfl_xor(csq[nf], 16);
        csq[nf]  += __shfl_xor(csq[nf], 32);
    }
    if (quad == 0) {
#pragma unroll
        for (int nf = 0; nf < 4; ++nf) {
            atomicAdd(&s_sum[wn * 64 + nf * 16 + lane16], csum[nf]);
            atomicAdd(&s_sq [wn * 64 + nf * 16 + lane16], csq[nf]);
        }
    }
    __syncthreads();
    if (t < BLKN) {
        atomicAdd(&colsum[col0 + t],   s_sum[t]);
        atomicAdd(&colsumsq[col0 + t], s_sq[t]);
    }
}

// ---------------------------------------------------------------------------
__global__ void bn_stats(const float* __restrict__ colsum,
                         const float* __restrict__ colsumsq,
                         float* __restrict__ mean, float* __restrict__ rstd) {
    int o = blockIdx.x * blockDim.x + threadIdx.x;
    float m = colsum[o] * (1.0f / B_ROWS);
    float v = colsumsq[o] * (1.0f / B_ROWS) - m * m;
    mean[o] = m;
    rstd[o] = rsqrtf(v + BN_EPS);
}

__global__ void bn_apply(float* __restrict__ out,
                         const float* __restrict__ mean,
                         const float* __restrict__ rstd) {
    size_t f = (size_t)blockIdx.x * blockDim.x + threadIdx.x;  // float4 index
    int c4 = (int)(f & (OUT_DIM / 4 - 1));
    float4 v = reinterpret_cast<float4*>(out)[f];
    float4 m = reinterpret_cast<const float4*>(mean)[c4];
    float4 r = reinterpret_cast<const float4*>(rstd)[c4];
    v.x = (v.x - m.x) * r.x;
    v.y = (v.y - m.y) * r.y;
    v.z = (v.z - m.z) * r.z;
    v.w = (v.w - m.w) * r.w;
    reinterpret_cast<float4*>(out)[f] = v;
}

// ---------------------------------------------------------------------------
extern "C" void kernel_launch(void* const* d_in, const int* in_sizes, int n_in,
                              void* d_out, int out_size, void* d_ws, size_t ws_size,
                              hipStream_t stream) {
    const float* x = (const float*)d_in[0];
    const float* w = (const float*)d_in[1];
    float* out = (float*)d_out;

    uint8_t* ws = (uint8_t*)d_ws;
    int8_t* xb = (int8_t*)ws;                                      // 33.55 MB
    int8_t* wb = (int8_t*)(ws + (size_t)B_ROWS * IN_DIM);          // 16.78 MB
    float* colsum   = (float*)(ws + (size_t)B_ROWS * IN_DIM
                                  + (size_t)OUT_DIM * IN_DIM);
    float* colsumsq = colsum + OUT_DIM;
    float* mean     = colsumsq + OUT_DIM;
    float* rstd     = mean + OUT_DIM;

    hipMemsetAsync(colsum, 0, 2 * OUT_DIM * sizeof(float), stream);

    pack_i8<<<(B_ROWS * IN_DIM / 4) / 256, 256, 0, stream>>>(x, (int*)xb);
    pack_i8<<<(OUT_DIM * IN_DIM / 4) / 256, 256, 0, stream>>>(w, (int*)wb);

    bin_gemm_i8<<<dim3(OUT_DIM / BLKN, B_ROWS / BM), 512, 0, stream>>>(
        xb, wb, out, colsum, colsumsq);

    bn_stats<<<OUT_DIM / 256, 256, 0, stream>>>(colsum, colsumsq, mean, rstd);

    bn_apply<<<(unsigned)((size_t)B_ROWS * OUT_DIM / 4 / 256), 256, 0, stream>>>(
        out, mean, rstd);
}